// Round 9
// baseline (668.458 us; speedup 1.0000x reference)
//
#include <hip/hip_runtime.h>

#define NN 8192
#define DD 112
#define KK 6            // k+1 entries per row
#define NCHUNK 16
#define CHUNKSZ (NN / NCHUNK)   // 512
#define TJ 32           // j-tile staged in LDS (14 KB)
#define NR 4            // rows per thread (register-blocked, share B reads)
#define RPB 256         // rows per block = 256 threads / 4 lanes * NR
#define F1 32
#define F2 8

typedef float f4 __attribute__((ext_vector_type(4)));
typedef float f2 __attribute__((ext_vector_type(2)));

// packed fma on f2: per-component IEEE fma, backend selects v_pk_fma_f32.
#if __has_builtin(__builtin_elementwise_fma)
#define PKFMA(acc, aa, bb) (acc) = __builtin_elementwise_fma((aa), (bb), (acc))
#else
#define PKFMA(acc, aa, bb)                          \
    do {                                            \
        f2 _a = (aa), _b = (bb);                    \
        (acc).x = fmaf(_a.x, _b.x, (acc).x);        \
        (acc).y = fmaf(_a.y, _b.y, (acc).y);        \
    } while (0)
#endif

// quad-perm DPP exchange-and-add: returns x + lane_swap(x) within quads.
template <int CTRL>
__device__ __forceinline__ float dpp_xor_add(float x) {
    int y = __builtin_amdgcn_update_dpp(0, __float_as_int(x), CTRL, 0xf, 0xf, true);
    return x + __int_as_float(y);
}
#define DPP_XOR1 0xB1   // quad_perm [1,0,3,2]
#define DPP_XOR2 0x4E   // quad_perm [2,3,0,1]

__device__ __forceinline__ void topk_insert(float d, int j, float (&v)[KK], int (&ix)[KK]) {
    if (d > v[KK - 1]) {
        v[KK - 1] = d; ix[KK - 1] = j;
#pragma unroll
        for (int p = KK - 1; p > 0; --p) {
            if (v[p] > v[p - 1]) {
                float tv = v[p]; v[p] = v[p - 1]; v[p - 1] = tv;
                int ti = ix[p]; ix[p] = ix[p - 1]; ix[p - 1] = ti;
            }
        }
    }
}

// ---------------- workspace layout (float offsets) ----------------
static const size_t OFF_H     = 0;
static const size_t OFF_XN    = OFF_H + (size_t)NN * DD;
static const size_t OFF_CANDV = OFF_XN + (size_t)NN * DD;
static const size_t OFF_CANDI = OFF_CANDV + (size_t)NN * NCHUNK * KK;
static const size_t OFF_TOPV  = OFF_CANDI + (size_t)NN * NCHUNK * KK;
static const size_t OFF_TOPI  = OFF_TOPV + (size_t)NN * KK;
static const size_t OFF_ROWS  = OFF_TOPI + (size_t)NN * KK;
static const size_t OFF_COLS  = OFF_ROWS + (size_t)NN;
static const size_t OFF_DINV  = OFF_COLS + (size_t)NN;
static const size_t OFF_GG    = OFF_DINV + (size_t)NN;
// GCN temporaries alias the candidate region — ONLY valid after k_merge has
// consumed candv/candi (zeroing must happen post-merge; round 6 lesson).
static const size_t OFF_Z1    = OFF_CANDV;                      // NN*F1
static const size_t OFF_ACC1  = OFF_Z1 + (size_t)NN * F1;       // NN*F1
static const size_t OFF_HH1   = OFF_ACC1 + (size_t)NN * F1;     // NN*F1
static const size_t OFF_Z2    = OFF_HH1 + (size_t)NN * F1;      // NN*F2
static const size_t OFF_ACC2  = OFF_Z2 + (size_t)NN * F2;       // NN*F2

__device__ __forceinline__ float lrelu(float x) { return x >= 0.f ? x : 0.01f * x; }

// ---------------- K1: conv1d + leaky + row norm; consts fold; zero colsum ----------
__global__ __launch_bounds__(256) void k_conv(const float* __restrict__ xraw,
                                              const float* __restrict__ cw,
                                              const float* __restrict__ cb,
                                              const float* __restrict__ ipw,
                                              const float* __restrict__ ipb,
                                              const float* __restrict__ opw,
                                              const float* __restrict__ opb,
                                              const float* __restrict__ clsw,
                                              const float* __restrict__ clsb,
                                              float* __restrict__ h, float* __restrict__ xn,
                                              float* __restrict__ colsum,
                                              float* __restrict__ Gg) {
    int i = blockIdx.x * 256 + threadIdx.x;
    float x[30];
#pragma unroll
    for (int t = 0; t < 30; ++t) x[t] = xraw[i * 30 + t];
    float hh[112];
    float ss = 0.f;
#pragma unroll
    for (int c = 0; c < 4; ++c) {
        float w0 = cw[c * 3 + 0], w1 = cw[c * 3 + 1], w2 = cw[c * 3 + 2], b = cb[c];
#pragma unroll
        for (int t = 0; t < 28; ++t) {
            float u = x[t] * w0 + x[t + 1] * w1 + x[t + 2] * w2 + b;
            u = lrelu(u);
            hh[c * 28 + t] = u;
            ss = fmaf(u, u, ss);
        }
    }
    float inv = 1.f / fmaxf(sqrtf(ss), 1e-12f);
#pragma unroll
    for (int t = 0; t < 112; ++t) {
        h[i * 112 + t] = hh[t];
        xn[i * 112 + t] = hh[t] * inv;
    }
    colsum[i] = 0.f;

    // fold attention+classifier constants on one thread
    if (blockIdx.x == 0 && threadIdx.x == 0) {
        float M[8][8], cv[8];
#pragma unroll
        for (int c = 0; c < 8; ++c) {
            float s = opb[c];
#pragma unroll
            for (int a = 0; a < 8; ++a) s = fmaf(opw[c * 8 + a], ipb[16 + a], s);
            cv[c] = s;
#pragma unroll
            for (int b = 0; b < 8; ++b) {
                float m = 0.f;
#pragma unroll
                for (int a = 0; a < 8; ++a) m = fmaf(opw[c * 8 + a], ipw[(16 + a) * 8 + b], m);
                M[c][b] = m;
            }
        }
#pragma unroll
        for (int o = 0; o < 2; ++o) {
#pragma unroll
            for (int e = 0; e < 8; ++e) {
                float s = clsw[o * 16 + e];
#pragma unroll
                for (int f = 0; f < 8; ++f) s = fmaf(clsw[o * 16 + 8 + f], M[f][e], s);
                Gg[o * 8 + e] = s;
            }
            float s = clsb[o];
#pragma unroll
            for (int f = 0; f < 8; ++f) s = fmaf(clsw[o * 16 + 8 + f], cv[f], s);
            Gg[16 + o] = s;
        }
    }
}

// ---------------- K2: KNN — 4 lanes/row quarter split, NR=4 rows/thread share B reads
// grid: (NCHUNK, NN/RPB) = (16, 32); block 256 threads; 2 blocks/CU
__global__ __launch_bounds__(256, 2) void k_knn(const float* __restrict__ xn,
                                                float* __restrict__ candv,
                                                int* __restrict__ candi) {
    __shared__ f4 tile[TJ * 28];   // 32 j-rows x 112 floats = 14 KB
    const int tid = threadIdx.x;
    const int q = tid & 3;             // which 28-float quarter of the row
    const int g = tid >> 2;            // group 0..63
    const int chunk = blockIdx.x;
    const int row0 = blockIdx.y * RPB + g;   // rows row0 + {0,64,128,192}
    const f4* __restrict__ xv = reinterpret_cast<const f4*>(xn);

    // each thread holds one quarter (7 f4) of NR rows -> 112 VGPRs row state
    f4 rr[NR][7];
#pragma unroll
    for (int r = 0; r < NR; ++r)
#pragma unroll
        for (int e = 0; e < 7; ++e)
            rr[r][e] = xv[(size_t)(row0 + r * 64) * 28 + q * 7 + e];

    float vv[NR][KK];
    int ii[NR][KK];
#pragma unroll
    for (int r = 0; r < NR; ++r)
#pragma unroll
        for (int t = 0; t < KK; ++t) { vv[r][t] = -3.0e38f; ii[r][t] = -1; }

    const int j0 = chunk * CHUNKSZ;

#pragma unroll 1
    for (int tt = 0; tt < CHUNKSZ / TJ; ++tt) {
        // stage 32 j-rows: 896 f4, linear & coalesced
        const f4* __restrict__ src = xv + (size_t)(j0 + tt * TJ) * 28;
        tile[tid] = src[tid];
        tile[tid + 256] = src[tid + 256];
        tile[tid + 512] = src[tid + 512];
        if (tid < 128) tile[tid + 768] = src[tid + 768];
        __syncthreads();

#pragma unroll 1
        for (int jj = 0; jj < TJ; ++jj) {
            const f4* __restrict__ xj = &tile[jj * 28 + q * 7];
            f2 a0[NR], a1[NR];
#pragma unroll
            for (int r = 0; r < NR; ++r) { a0[r] = (f2)(0.f); a1[r] = (f2)(0.f); }
#pragma unroll
            for (int e = 0; e < 7; ++e) {
                f4 b = xj[e];
#pragma unroll
                for (int r = 0; r < NR; ++r) {
                    PKFMA(a0[r], rr[r][e].xy, b.xy);
                    PKFMA(a1[r], rr[r][e].zw, b.zw);
                }
            }
            int j = j0 + tt * TJ + jj;
#pragma unroll
            for (int r = 0; r < NR; ++r) {
                // quarter dot (same order as prior rounds), then quad butterfly
                float d = (a0[r].x + a0[r].y) + (a1[r].x + a1[r].y);
                d = dpp_xor_add<DPP_XOR1>(d);
                d = dpp_xor_add<DPP_XOR2>(d);
                topk_insert(d, j, vv[r], ii[r]);
            }
        }
        __syncthreads();
    }

    if (q == 0) {
#pragma unroll
        for (int r = 0; r < NR; ++r) {
            size_t base = (size_t)(row0 + r * 64) * (NCHUNK * KK) + (size_t)chunk * KK;
#pragma unroll
            for (int t = 0; t < KK; ++t) {
                candv[base + t] = vv[r][t];
                candi[base + t] = ii[r][t];
            }
        }
    }
}

// ---------------- K3: merge 16x6 candidates -> top-6; rowsum; atomic colsum ----------------
__global__ __launch_bounds__(64) void k_merge(const float* __restrict__ cv,
                                              const int* __restrict__ ci,
                                              float* __restrict__ tv, int* __restrict__ ti,
                                              float* __restrict__ rowsum,
                                              float* __restrict__ colsum) {
    int i = blockIdx.x * 64 + threadIdx.x;
    const float* cvr = cv + (size_t)i * (NCHUNK * KK);
    const int* cir = ci + (size_t)i * (NCHUNK * KK);
    float sv[KK];
    int si[KK];
#pragma unroll
    for (int r = 0; r < KK; ++r) {
        float bv = -3.0e38f;
        int bi = 0x7fffffff;
        for (int c = 0; c < NCHUNK * KK; ++c) {
            float vvv = cvr[c];
            int iii = cir[c];
            if (iii < 0) continue;
            bool used = false;
#pragma unroll
            for (int u = 0; u < KK; ++u)
                if (u < r && si[u] == iii) used = true;
            if (!used && (vvv > bv || (vvv == bv && iii < bi))) { bv = vvv; bi = iii; }
        }
        sv[r] = bv;
        si[r] = bi;
    }
    float rs = 0.f;
#pragma unroll
    for (int r = 0; r < KK; ++r) {
        rs += sv[r];
        tv[(size_t)i * KK + r] = sv[r];
        ti[(size_t)i * KK + r] = si[r];
        atomicAdd(&colsum[si[r]], sv[r]);
    }
    rowsum[i] = rs;
}

// ---------------- K4: deg -> d^-1/2; zero acc1/acc2 (AFTER merge consumed cands) --------
__global__ __launch_bounds__(256) void k_degzero(const float* __restrict__ rowsum,
                                                 const float* __restrict__ colsum,
                                                 float* __restrict__ dinv,
                                                 float* __restrict__ acc1,
                                                 float* __restrict__ acc2) {
    int t = blockIdx.x * 256 + threadIdx.x;           // grid covers NN*F1
    acc1[t] = 0.f;
    if (t < NN * F2) acc2[t] = 0.f;
    if (t < NN) {
        float deg = 0.5f * (rowsum[t] + colsum[t]) + 1.0f;  // +1 for identity
        dinv[t] = 1.0f / sqrtf(deg);
    }
}

// ---------------- K5/K8: Z = dinv*(X@W), then scatter transpose edges ----------------
template <int DIN, int FOUT>
__global__ __launch_bounds__(256) void k_zscat(const float* __restrict__ x,
                                               const float* __restrict__ w,
                                               const float* __restrict__ dinv,
                                               const float* __restrict__ tv,
                                               const int* __restrict__ ti,
                                               float* __restrict__ z,
                                               float* __restrict__ acc) {
    int t = blockIdx.x * 256 + threadIdx.x;
    int i = t / FOUT, f = t % FOUT;
    float s = 0.f;
    for (int d = 0; d < DIN; ++d) s = fmaf(x[(size_t)i * DIN + d], w[d * FOUT + f], s);
    float zi = dinv[i] * s;
    z[t] = zi;
#pragma unroll
    for (int r = 0; r < KK; ++r) {
        float val = tv[(size_t)i * KK + r];
        int j = ti[(size_t)i * KK + r];
        atomicAdd(&acc[(size_t)j * FOUT + f], 0.5f * val * zi);
    }
}

// ---------------- K7: H1 = leaky(dinv*(Z + 0.5*gather + acc) + b) ----------------
template <int FOUT>
__global__ __launch_bounds__(256) void k_fin(const float* __restrict__ z,
                                             const float* __restrict__ tv,
                                             const int* __restrict__ ti,
                                             const float* __restrict__ acc,
                                             const float* __restrict__ dinv,
                                             const float* __restrict__ b,
                                             float* __restrict__ out) {
    int t = blockIdx.x * 256 + threadIdx.x;
    int i = t / FOUT, f = t % FOUT;
    float s = z[t] + acc[t];
#pragma unroll
    for (int r = 0; r < KK; ++r) {
        float val = tv[(size_t)i * KK + r];
        int j = ti[(size_t)i * KK + r];
        s = fmaf(0.5f * val, z[(size_t)j * FOUT + f], s);
    }
    out[t] = lrelu(fmaf(dinv[i], s, 0.f) + b[f]);
}

// ---------------- K10: layer-2 finalize + folded attention/classifier ----------------
__global__ __launch_bounds__(64) void k_out(const float* __restrict__ z2,
                                            const float* __restrict__ tv,
                                            const int* __restrict__ ti,
                                            const float* __restrict__ acc2,
                                            const float* __restrict__ dinv,
                                            const float* __restrict__ b2,
                                            const float* __restrict__ Gg,
                                            float* __restrict__ out) {
    int i = blockIdx.x * 64 + threadIdx.x;
    float hr[8];
#pragma unroll
    for (int f = 0; f < 8; ++f) {
        float s = z2[(size_t)i * 8 + f] + acc2[(size_t)i * 8 + f];
#pragma unroll
        for (int r = 0; r < KK; ++r) {
            float val = tv[(size_t)i * KK + r];
            int j = ti[(size_t)i * KK + r];
            s = fmaf(0.5f * val, z2[(size_t)j * 8 + f], s);
        }
        hr[f] = lrelu(dinv[i] * s + b2[f]);
    }
    float o0 = Gg[16], o1 = Gg[17];
#pragma unroll
    for (int e = 0; e < 8; ++e) {
        o0 = fmaf(Gg[e], hr[e], o0);
        o1 = fmaf(Gg[8 + e], hr[e], o1);
    }
    out[(size_t)i * 2 + 0] = o0;
    out[(size_t)i * 2 + 1] = o1;
}

extern "C" void kernel_launch(void* const* d_in, const int* in_sizes, int n_in,
                              void* d_out, int out_size, void* d_ws, size_t ws_size,
                              hipStream_t stream) {
    const float* xraw = (const float*)d_in[0];
    const float* convw = (const float*)d_in[2];
    const float* convb = (const float*)d_in[3];
    const float* rw1 = (const float*)d_in[4];
    const float* rb1 = (const float*)d_in[5];
    const float* rw2 = (const float*)d_in[6];
    const float* rb2 = (const float*)d_in[7];
    const float* ipw = (const float*)d_in[12];
    const float* ipb = (const float*)d_in[13];
    const float* opw = (const float*)d_in[14];
    const float* opb = (const float*)d_in[15];
    const float* clsw = (const float*)d_in[22];
    const float* clsb = (const float*)d_in[23];

    float* ws = (float*)d_ws;
    float* h = ws + OFF_H;
    float* xn = ws + OFF_XN;
    float* candv = ws + OFF_CANDV;
    int* candi = (int*)(ws + OFF_CANDI);
    float* topv = ws + OFF_TOPV;
    int* topi = (int*)(ws + OFF_TOPI);
    float* rowsum = ws + OFF_ROWS;
    float* colsum = ws + OFF_COLS;
    float* dinv = ws + OFF_DINV;
    float* Gg = ws + OFF_GG;
    float* z1 = ws + OFF_Z1;
    float* acc1 = ws + OFF_ACC1;
    float* hh1 = ws + OFF_HH1;
    float* z2 = ws + OFF_Z2;
    float* acc2 = ws + OFF_ACC2;

    k_conv<<<NN / 256, 256, 0, stream>>>(xraw, convw, convb, ipw, ipb, opw, opb, clsw, clsb,
                                         h, xn, colsum, Gg);
    k_knn<<<dim3(NCHUNK, NN / RPB), 256, 0, stream>>>(xn, candv, candi);
    k_merge<<<NN / 64, 64, 0, stream>>>(candv, candi, topv, topi, rowsum, colsum);
    k_degzero<<<(NN * F1) / 256, 256, 0, stream>>>(rowsum, colsum, dinv, acc1, acc2);

    k_zscat<DD, F1><<<(NN * F1) / 256, 256, 0, stream>>>(h, rw1, dinv, topv, topi, z1, acc1);
    k_fin<F1><<<(NN * F1) / 256, 256, 0, stream>>>(z1, topv, topi, acc1, dinv, rb1, hh1);

    k_zscat<F1, F2><<<(NN * F2) / 256, 256, 0, stream>>>(hh1, rw2, dinv, topv, topi, z2, acc2);
    k_out<<<NN / 64, 64, 0, stream>>>(z2, topv, topi, acc2, dinv, rb2, Gg, (float*)d_out);
}

// Round 10
// 437.828 us; speedup vs baseline: 1.5268x; 1.5268x over previous
//
#include <hip/hip_runtime.h>

#define NN 8192
#define DD 112
#define KK 6            // k+1 entries per row
#define NCHUNK 16
#define CHUNKSZ (NN / NCHUNK)   // 512
#define TJ 32           // j-tile staged in LDS (14 KB)
#define RPB 128         // rows per block (256 threads / 4 lanes-per-row * 2 rows)
#define F1 32
#define F2 8

typedef float f4 __attribute__((ext_vector_type(4)));
typedef float f2 __attribute__((ext_vector_type(2)));

// packed fma on f2: per-component IEEE fma, backend selects v_pk_fma_f32.
#if __has_builtin(__builtin_elementwise_fma)
#define PKFMA(acc, aa, bb) (acc) = __builtin_elementwise_fma((aa), (bb), (acc))
#else
#define PKFMA(acc, aa, bb)                          \
    do {                                            \
        f2 _a = (aa), _b = (bb);                    \
        (acc).x = fmaf(_a.x, _b.x, (acc).x);        \
        (acc).y = fmaf(_a.y, _b.y, (acc).y);        \
    } while (0)
#endif

// quad-perm DPP exchange-and-add: returns x + lane_swap(x) within quads.
template <int CTRL>
__device__ __forceinline__ float dpp_xor_add(float x) {
    int y = __builtin_amdgcn_update_dpp(0, __float_as_int(x), CTRL, 0xf, 0xf, true);
    return x + __int_as_float(y);
}
#define DPP_XOR1 0xB1   // quad_perm [1,0,3,2]
#define DPP_XOR2 0x4E   // quad_perm [2,3,0,1]

// ---------------- workspace layout (float offsets) ----------------
static const size_t OFF_H     = 0;
static const size_t OFF_XN    = OFF_H + (size_t)NN * DD;
static const size_t OFF_CANDV = OFF_XN + (size_t)NN * DD;
static const size_t OFF_CANDI = OFF_CANDV + (size_t)NN * NCHUNK * KK;
static const size_t OFF_TOPV  = OFF_CANDI + (size_t)NN * NCHUNK * KK;
static const size_t OFF_TOPI  = OFF_TOPV + (size_t)NN * KK;
static const size_t OFF_ROWS  = OFF_TOPI + (size_t)NN * KK;
static const size_t OFF_COLS  = OFF_ROWS + (size_t)NN;
static const size_t OFF_DINV  = OFF_COLS + (size_t)NN;
static const size_t OFF_GG    = OFF_DINV + (size_t)NN;
// GCN temporaries alias the candidate region — ONLY valid after k_merge has
// consumed candv/candi (zeroing must happen post-merge; round 6 lesson).
static const size_t OFF_Z1    = OFF_CANDV;                      // NN*F1
static const size_t OFF_ACC1  = OFF_Z1 + (size_t)NN * F1;       // NN*F1
static const size_t OFF_HH1   = OFF_ACC1 + (size_t)NN * F1;     // NN*F1
static const size_t OFF_Z2    = OFF_HH1 + (size_t)NN * F1;      // NN*F2
static const size_t OFF_ACC2  = OFF_Z2 + (size_t)NN * F2;       // NN*F2

__device__ __forceinline__ float lrelu(float x) { return x >= 0.f ? x : 0.01f * x; }

// ---------------- K1: conv1d + leaky + row norm (f4 stores); consts fold; zero colsum --
__global__ __launch_bounds__(64) void k_conv(const float* __restrict__ xraw,
                                             const float* __restrict__ cw,
                                             const float* __restrict__ cb,
                                             const float* __restrict__ ipw,
                                             const float* __restrict__ ipb,
                                             const float* __restrict__ opw,
                                             const float* __restrict__ opb,
                                             const float* __restrict__ clsw,
                                             const float* __restrict__ clsb,
                                             float* __restrict__ h, float* __restrict__ xn,
                                             float* __restrict__ colsum,
                                             float* __restrict__ Gg) {
    int i = blockIdx.x * 64 + threadIdx.x;
    float x[30];
#pragma unroll
    for (int t = 0; t < 30; ++t) x[t] = xraw[i * 30 + t];
    float hh[112];
    float ss = 0.f;
#pragma unroll
    for (int c = 0; c < 4; ++c) {
        float w0 = cw[c * 3 + 0], w1 = cw[c * 3 + 1], w2 = cw[c * 3 + 2], b = cb[c];
#pragma unroll
        for (int t = 0; t < 28; ++t) {
            float u = x[t] * w0 + x[t + 1] * w1 + x[t + 2] * w2 + b;
            u = lrelu(u);
            hh[c * 28 + t] = u;
            ss = fmaf(u, u, ss);
        }
    }
    float inv = 1.f / fmaxf(sqrtf(ss), 1e-12f);
    f4* __restrict__ hv = reinterpret_cast<f4*>(h);
    f4* __restrict__ xv = reinterpret_cast<f4*>(xn);
#pragma unroll
    for (int t = 0; t < 28; ++t) {
        f4 u;
        u.x = hh[t * 4 + 0]; u.y = hh[t * 4 + 1];
        u.z = hh[t * 4 + 2]; u.w = hh[t * 4 + 3];
        hv[(size_t)i * 28 + t] = u;
        f4 un;
        un.x = u.x * inv; un.y = u.y * inv; un.z = u.z * inv; un.w = u.w * inv;
        xv[(size_t)i * 28 + t] = un;
    }
    colsum[i] = 0.f;

    // fold attention+classifier constants on one thread
    if (blockIdx.x == 0 && threadIdx.x == 0) {
        float M[8][8], cv[8];
#pragma unroll
        for (int c = 0; c < 8; ++c) {
            float s = opb[c];
#pragma unroll
            for (int a = 0; a < 8; ++a) s = fmaf(opw[c * 8 + a], ipb[16 + a], s);
            cv[c] = s;
#pragma unroll
            for (int b = 0; b < 8; ++b) {
                float m = 0.f;
#pragma unroll
                for (int a = 0; a < 8; ++a) m = fmaf(opw[c * 8 + a], ipw[(16 + a) * 8 + b], m);
                M[c][b] = m;
            }
        }
#pragma unroll
        for (int o = 0; o < 2; ++o) {
#pragma unroll
            for (int e = 0; e < 8; ++e) {
                float s = clsw[o * 16 + e];
#pragma unroll
                for (int f = 0; f < 8; ++f) s = fmaf(clsw[o * 16 + 8 + f], M[f][e], s);
                Gg[o * 8 + e] = s;
            }
            float s = clsb[o];
#pragma unroll
            for (int f = 0; f < 8; ++f) s = fmaf(clsw[o * 16 + 8 + f], cv[f], s);
            Gg[16 + o] = s;
        }
    }
}

// ---------------- K2: KNN — 4 lanes per row (quarter-dot + DPP butterfly), 2 rows/thread
// grid: (NCHUNK, NN/RPB) = (16, 64); block 256 threads; 4 blocks/CU
// (round-7 verified config: jointly DS+VALU saturated at ~325 us)
__global__ __launch_bounds__(256, 4) void k_knn(const float* __restrict__ xn,
                                                float* __restrict__ candv,
                                                int* __restrict__ candi) {
    __shared__ f4 tile[TJ * 28];   // 32 j-rows x 112 floats = 14 KB
    const int tid = threadIdx.x;
    const int q = tid & 3;             // which 28-float quarter of the row
    const int g = tid >> 2;            // group 0..63
    const int chunk = blockIdx.x;
    const int rowA = blockIdx.y * RPB + g;
    const int rowB = rowA + 64;
    const f4* __restrict__ xv = reinterpret_cast<const f4*>(xn);

    // each thread holds one quarter (7 f4) of two rows -> 56 VGPRs
    f4 rA[7], rB[7];
#pragma unroll
    for (int e = 0; e < 7; ++e) rA[e] = xv[(size_t)rowA * 28 + q * 7 + e];
#pragma unroll
    for (int e = 0; e < 7; ++e) rB[e] = xv[(size_t)rowB * 28 + q * 7 + e];

    float vA[KK], vB[KK];
    int iA[KK], iB[KK];
#pragma unroll
    for (int t = 0; t < KK; ++t) {
        vA[t] = -3.0e38f; iA[t] = -1;
        vB[t] = -3.0e38f; iB[t] = -1;
    }
    const int j0 = chunk * CHUNKSZ;

#pragma unroll 1
    for (int tt = 0; tt < CHUNKSZ / TJ; ++tt) {
        // stage 32 j-rows: 896 f4, linear & coalesced
        const f4* __restrict__ src = xv + (size_t)(j0 + tt * TJ) * 28;
        tile[tid] = src[tid];
        tile[tid + 256] = src[tid + 256];
        tile[tid + 512] = src[tid + 512];
        if (tid < 128) tile[tid + 768] = src[tid + 768];
        __syncthreads();

#pragma unroll 1
        for (int jj = 0; jj < TJ; ++jj) {
            const f4* __restrict__ xj = &tile[jj * 28 + q * 7];
            f2 a0A = (f2)(0.f), a1A = (f2)(0.f), a0B = (f2)(0.f), a1B = (f2)(0.f);
#pragma unroll
            for (int e = 0; e < 7; ++e) {
                f4 b = xj[e];
                PKFMA(a0A, rA[e].xy, b.xy);
                PKFMA(a1A, rA[e].zw, b.zw);
                PKFMA(a0B, rB[e].xy, b.xy);
                PKFMA(a1B, rB[e].zw, b.zw);
            }
            // quarter dots (same order as prior rounds)
            float dA = (a0A.x + a0A.y) + (a1A.x + a1A.y);
            float dB = (a0B.x + a0B.y) + (a1B.x + a1B.y);
            // butterfly across the 4 lanes of the quad: ((Q0+Q1)+(Q2+Q3)), same bits on all 4
            dA = dpp_xor_add<DPP_XOR1>(dA);
            dA = dpp_xor_add<DPP_XOR2>(dA);
            dB = dpp_xor_add<DPP_XOR1>(dB);
            dB = dpp_xor_add<DPP_XOR2>(dB);

            int j = j0 + tt * TJ + jj;
            if (dA > vA[KK - 1]) {
                vA[KK - 1] = dA; iA[KK - 1] = j;
#pragma unroll
                for (int p = KK - 1; p > 0; --p) {
                    if (vA[p] > vA[p - 1]) {
                        float tv = vA[p]; vA[p] = vA[p - 1]; vA[p - 1] = tv;
                        int ti = iA[p]; iA[p] = iA[p - 1]; iA[p - 1] = ti;
                    }
                }
            }
            if (dB > vB[KK - 1]) {
                vB[KK - 1] = dB; iB[KK - 1] = j;
#pragma unroll
                for (int p = KK - 1; p > 0; --p) {
                    if (vB[p] > vB[p - 1]) {
                        float tv = vB[p]; vB[p] = vB[p - 1]; vB[p - 1] = tv;
                        int ti = iB[p]; iB[p] = iB[p - 1]; iB[p - 1] = ti;
                    }
                }
            }
        }
        __syncthreads();
    }

    if (q == 0) {
        size_t baseA = (size_t)rowA * (NCHUNK * KK) + (size_t)chunk * KK;
        size_t baseB = (size_t)rowB * (NCHUNK * KK) + (size_t)chunk * KK;
#pragma unroll
        for (int t = 0; t < KK; ++t) {
            candv[baseA + t] = vA[t];
            candi[baseA + t] = iA[t];
            candv[baseB + t] = vB[t];
            candi[baseB + t] = iB[t];
        }
    }
}

// ---------------- K3: merge 16x6 candidates -> top-6 (stable insertion scan) -----------
// Chunk candidate index sets are disjoint, so no dedup needed. Scan order
// (chunk asc, then value-desc-within-chunk with lower-j-first on ties) + strict >
// insertion reproduces the (value desc, index asc) selection of the old O(R*C*R)
// scan bitwise — same set, same order, same rowsum accumulation order.
__global__ __launch_bounds__(64) void k_merge(const float* __restrict__ cv,
                                              const int* __restrict__ ci,
                                              float* __restrict__ tv, int* __restrict__ ti,
                                              float* __restrict__ rowsum,
                                              float* __restrict__ colsum) {
    int i = blockIdx.x * 64 + threadIdx.x;
    const float* cvr = cv + (size_t)i * (NCHUNK * KK);
    const int* cir = ci + (size_t)i * (NCHUNK * KK);
    float sv[KK];
    int si[KK];
#pragma unroll
    for (int t = 0; t < KK; ++t) { sv[t] = -3.0e38f; si[t] = -1; }
#pragma unroll 4
    for (int c = 0; c < NCHUNK * KK; ++c) {
        float d = cvr[c];
        int j = cir[c];
        if (d > sv[KK - 1]) {
            sv[KK - 1] = d; si[KK - 1] = j;
#pragma unroll
            for (int p = KK - 1; p > 0; --p) {
                if (sv[p] > sv[p - 1]) {
                    float tw = sv[p]; sv[p] = sv[p - 1]; sv[p - 1] = tw;
                    int tj = si[p]; si[p] = si[p - 1]; si[p - 1] = tj;
                }
            }
        }
    }
    float rs = 0.f;
#pragma unroll
    for (int r = 0; r < KK; ++r) {
        rs += sv[r];
        tv[(size_t)i * KK + r] = sv[r];
        ti[(size_t)i * KK + r] = si[r];
        atomicAdd(&colsum[si[r]], sv[r]);
    }
    rowsum[i] = rs;
}

// ---------------- K4: deg -> d^-1/2; zero acc1/acc2 (AFTER merge consumed cands) --------
__global__ __launch_bounds__(256) void k_degzero(const float* __restrict__ rowsum,
                                                 const float* __restrict__ colsum,
                                                 float* __restrict__ dinv,
                                                 float* __restrict__ acc1,
                                                 float* __restrict__ acc2) {
    int t = blockIdx.x * 256 + threadIdx.x;           // grid covers NN*F1
    acc1[t] = 0.f;
    if (t < NN * F2) acc2[t] = 0.f;
    if (t < NN) {
        float deg = 0.5f * (rowsum[t] + colsum[t]) + 1.0f;  // +1 for identity
        dinv[t] = 1.0f / sqrtf(deg);
    }
}

// ---------------- K5/K8: Z = dinv*(X@W), then scatter transpose edges ----------------
template <int DIN, int FOUT>
__global__ __launch_bounds__(256) void k_zscat(const float* __restrict__ x,
                                               const float* __restrict__ w,
                                               const float* __restrict__ dinv,
                                               const float* __restrict__ tv,
                                               const int* __restrict__ ti,
                                               float* __restrict__ z,
                                               float* __restrict__ acc) {
    int t = blockIdx.x * 256 + threadIdx.x;
    int i = t / FOUT, f = t % FOUT;
    float s = 0.f;
    for (int d = 0; d < DIN; ++d) s = fmaf(x[(size_t)i * DIN + d], w[d * FOUT + f], s);
    float zi = dinv[i] * s;
    z[t] = zi;
#pragma unroll
    for (int r = 0; r < KK; ++r) {
        float val = tv[(size_t)i * KK + r];
        int j = ti[(size_t)i * KK + r];
        atomicAdd(&acc[(size_t)j * FOUT + f], 0.5f * val * zi);
    }
}

// ---------------- K7: H1 = leaky(dinv*(Z + 0.5*gather + acc) + b) ----------------
template <int FOUT>
__global__ __launch_bounds__(256) void k_fin(const float* __restrict__ z,
                                             const float* __restrict__ tv,
                                             const int* __restrict__ ti,
                                             const float* __restrict__ acc,
                                             const float* __restrict__ dinv,
                                             const float* __restrict__ b,
                                             float* __restrict__ out) {
    int t = blockIdx.x * 256 + threadIdx.x;
    int i = t / FOUT, f = t % FOUT;
    float s = z[t] + acc[t];
#pragma unroll
    for (int r = 0; r < KK; ++r) {
        float val = tv[(size_t)i * KK + r];
        int j = ti[(size_t)i * KK + r];
        s = fmaf(0.5f * val, z[(size_t)j * FOUT + f], s);
    }
    out[t] = lrelu(fmaf(dinv[i], s, 0.f) + b[f]);
}

// ---------------- K10: layer-2 finalize + folded attention/classifier ----------------
__global__ __launch_bounds__(64) void k_out(const float* __restrict__ z2,
                                            const float* __restrict__ tv,
                                            const int* __restrict__ ti,
                                            const float* __restrict__ acc2,
                                            const float* __restrict__ dinv,
                                            const float* __restrict__ b2,
                                            const float* __restrict__ Gg,
                                            float* __restrict__ out) {
    int i = blockIdx.x * 64 + threadIdx.x;
    float hr[8];
#pragma unroll
    for (int f = 0; f < 8; ++f) {
        float s = z2[(size_t)i * 8 + f] + acc2[(size_t)i * 8 + f];
#pragma unroll
        for (int r = 0; r < KK; ++r) {
            float val = tv[(size_t)i * KK + r];
            int j = ti[(size_t)i * KK + r];
            s = fmaf(0.5f * val, z2[(size_t)j * 8 + f], s);
        }
        hr[f] = lrelu(dinv[i] * s + b2[f]);
    }
    float o0 = Gg[16], o1 = Gg[17];
#pragma unroll
    for (int e = 0; e < 8; ++e) {
        o0 = fmaf(Gg[e], hr[e], o0);
        o1 = fmaf(Gg[8 + e], hr[e], o1);
    }
    out[(size_t)i * 2 + 0] = o0;
    out[(size_t)i * 2 + 1] = o1;
}

extern "C" void kernel_launch(void* const* d_in, const int* in_sizes, int n_in,
                              void* d_out, int out_size, void* d_ws, size_t ws_size,
                              hipStream_t stream) {
    const float* xraw = (const float*)d_in[0];
    const float* convw = (const float*)d_in[2];
    const float* convb = (const float*)d_in[3];
    const float* rw1 = (const float*)d_in[4];
    const float* rb1 = (const float*)d_in[5];
    const float* rw2 = (const float*)d_in[6];
    const float* rb2 = (const float*)d_in[7];
    const float* ipw = (const float*)d_in[12];
    const float* ipb = (const float*)d_in[13];
    const float* opw = (const float*)d_in[14];
    const float* opb = (const float*)d_in[15];
    const float* clsw = (const float*)d_in[22];
    const float* clsb = (const float*)d_in[23];

    float* ws = (float*)d_ws;
    float* h = ws + OFF_H;
    float* xn = ws + OFF_XN;
    float* candv = ws + OFF_CANDV;
    int* candi = (int*)(ws + OFF_CANDI);
    float* topv = ws + OFF_TOPV;
    int* topi = (int*)(ws + OFF_TOPI);
    float* rowsum = ws + OFF_ROWS;
    float* colsum = ws + OFF_COLS;
    float* dinv = ws + OFF_DINV;
    float* Gg = ws + OFF_GG;
    float* z1 = ws + OFF_Z1;
    float* acc1 = ws + OFF_ACC1;
    float* hh1 = ws + OFF_HH1;
    float* z2 = ws + OFF_Z2;
    float* acc2 = ws + OFF_ACC2;

    k_conv<<<NN / 64, 64, 0, stream>>>(xraw, convw, convb, ipw, ipb, opw, opb, clsw, clsb,
                                       h, xn, colsum, Gg);
    k_knn<<<dim3(NCHUNK, NN / RPB), 256, 0, stream>>>(xn, candv, candi);
    k_merge<<<NN / 64, 64, 0, stream>>>(candv, candi, topv, topi, rowsum, colsum);
    k_degzero<<<(NN * F1) / 256, 256, 0, stream>>>(rowsum, colsum, dinv, acc1, acc2);

    k_zscat<DD, F1><<<(NN * F1) / 256, 256, 0, stream>>>(h, rw1, dinv, topv, topi, z1, acc1);
    k_fin<F1><<<(NN * F1) / 256, 256, 0, stream>>>(z1, topv, topi, acc1, dinv, rb1, hh1);

    k_zscat<F1, F2><<<(NN * F2) / 256, 256, 0, stream>>>(hh1, rw2, dinv, topv, topi, z2, acc2);
    k_out<<<NN / 64, 64, 0, stream>>>(z2, topv, topi, acc2, dinv, rb2, Gg, (float*)d_out);
}